// Round 14
// baseline (27.576 us; speedup 1.0000x reference)
//
#include <hip/hip_runtime.h>
#include <hip/hip_fp16.h>
#include <stdint.h>

#define NR 5000
#define NRM1 4999
#define W 640
#define NBLK 2500          // block b: rows b and 4998-b == virtual space of 5000 elems
#define NG 5               // float4 groups per thread: 5*4*256 = 5120 >= 5000
#define PCOUNT 12497500.0f
#define LOG2E 1.44269504088896340736f
#define LN2   0.69314718055994530942f

typedef float float4u __attribute__((ext_vector_type(4)));
struct __attribute__((packed, aligned(4))) f4wrap { float4u v; };
__device__ __forceinline__ float4u load4u(const float* p) {
    return ((const f4wrap*)p)->v;    // 4B-aligned vector load
}

// ---------------- Kernel 1: gather zs = half(x[rows,cols] * log2e) ----------------
__global__ void gather_z(const float* __restrict__ x,
                         const int* __restrict__ centers,
                         __half* __restrict__ zs) {
    int t = blockIdx.x * blockDim.x + threadIdx.x;
    if (t < NR) {
        const int2 rc = ((const int2*)centers)[t];
        zs[t] = __float2half(x[rc.x * W + rc.y] * LOG2E);
    } else if (t < NR + 2) {
        zs[t] = __float2half(0.0f);                 // pad for staggered staging
    }
}

// Loss per element, log2 domain (ln2 applied in final_reduce), branchless:
//   s = zs_j - zs_r  (= (z_j - z_r)*log2e = -d*log2e)
//   t = g*s -> 2^t = exp(-g*d);  lg = log2(1+2^t) = softplus(-g*d)/ln2
//   q = s^2*ln2 = d^2/ln2;  m = g^2 in {0,1};  l = q + m*(lg - q)
__global__ __launch_bounds__(256) void pair_loss(const float* __restrict__ gt,
                                                 const __half* __restrict__ zs,
                                                 float* __restrict__ partials) {
    __shared__ __half2 A2[NR / 2 + 2];   // (zs[2t],   zs[2t+1])
    __shared__ __half2 B2[NR / 2 + 2];   // (zs[2t+1], zs[2t+2])  parity-staggered
    __shared__ float wsum[4];
    const int tid = threadIdx.x;
    const int b = blockIdx.x;

    const __half2* __restrict__ zs2 = (const __half2*)zs;
    for (int t = tid; t < NR / 2; t += 256) {
        const __half2 a  = zs2[t];
        const __half2 an = zs2[t + 1];              // t+1<=2500: reads pad halves
        A2[t] = a;
        B2[t] = __halves2half2(__high2half(a), __low2half(an));
    }
    __syncthreads();

    const __half* __restrict__ szh = (const __half*)A2;

    const int r1 = b, r2 = NR - 2 - b;
    const int len1 = NRM1 - r1;                     // 4999-b
    const int off1 = r1 * NRM1 - (r1 * (r1 - 1)) / 2;
    const int off2 = r2 * NRM1 - (r2 * (r2 - 1)) / 2;
    const int off2v = off2 - len1;
    const int vmax = (r2 > r1) ? 5000 : len1;       // multiples of 4
    const __half zr1h = szh[r1], zr2h = szh[r2];
    const __half2 zr1h2 = __half2half2(zr1h), zr2h2 = __half2half2(zr2h);
    const float zr1f = __half2float(zr1h), zr2f = __half2float(zr2h);

    // ---- batch-issue NG float4 gt loads (independent, fully unrolled) ----
    float4u g4[NG];
    int cb[NG];
    #pragma unroll
    for (int k = 0; k < NG; ++k) {
        const int vb = 4 * tid + 1024 * k;
        const int c = min(vb, vmax - 4);
        cb[k] = c;
        const float* base = (c < len1) ? (gt + off1) : (gt + off2v);
        g4[k] = load4u(base + c);
    }

    const __half2 one2  = __float2half2_rn(1.0f);
    const __half2 zero2 = __float2half2_rn(0.0f);
    const __half2 ln2h2 = __float2half2_rn(LN2);
    __half2 accA = zero2, accB = zero2;
    float accS = 0.0f;                              // straddle fallback acc (f32)

    #pragma unroll
    for (int k = 0; k < NG; ++k) {
        const int c = cb[k];
        const int vb = 4 * tid + 1024 * k;
        const bool in1 = c < len1;
        const bool straddle = in1 && (c + 3 >= len1);
        if (!straddle) {
            const int ib = c + (in1 ? r1 + 1 : 0);
            const __half2* __restrict__ arr = (ib & 1) ? B2 : A2;
            const int i0 = ib >> 1;
            const __half2 zj01 = arr[i0];
            const __half2 zj23 = arr[i0 + 1];
            const __half2 zrh2 = in1 ? zr1h2 : zr2h2;
            const __half2 g01 = __float22half2_rn(make_float2(g4[k].x, g4[k].y));
            const __half2 g23 = __float22half2_rn(make_float2(g4[k].z, g4[k].w));
            const __half2 s01 = __hsub2(zj01, zrh2), s23 = __hsub2(zj23, zrh2);
            const __half2 t01 = __hmul2(g01, s01),  t23 = __hmul2(g23, s23);
            const __half2 p01 = __hadd2(h2exp2(t01), one2);
            const __half2 p23 = __hadd2(h2exp2(t23), one2);
            const __half2 lg01 = h2log2(p01), lg23 = h2log2(p23);
            const __half2 q01 = __hmul2(__hmul2(s01, s01), ln2h2);
            const __half2 q23 = __hmul2(__hmul2(s23, s23), ln2h2);
            const __half2 m01 = __hmul2(g01, g01), m23 = __hmul2(g23, g23);
            const __half2 l01 = __hfma2(m01, __hsub2(lg01, q01), q01);
            const __half2 l23 = __hfma2(m23, __hsub2(lg23, q23), q23);
            const __half2 w2 = (vb < vmax) ? one2 : zero2;   // group-uniform
            accA = __hfma2(l01, w2, accA);
            accB = __hfma2(l23, w2, accB);
        } else if (vb < vmax) {
            // rare: <=1 group/block spans the row1/row2 junction; scalar f32 path
            #pragma unroll
            for (int e = 0; e < 4; ++e) {
                const int ce = c + e;
                const bool i1 = ce < len1;
                const float zj = __half2float(szh[ce + (i1 ? r1 + 1 : 0)]);
                const float zr = i1 ? zr1f : zr2f;
                const float g = gt[(i1 ? off1 : off2v) + ce];
                const float s = zj - zr;
                const float lg = __log2f(1.0f + exp2f(g * s));
                accS += (g != 0.0f) ? lg : s * s * LN2;
            }
        }
    }

    const float2 fA = __half22float2(accA);
    const float2 fB = __half22float2(accB);
    float acc = ((fA.x + fA.y) + (fB.x + fB.y)) + accS;

    // deterministic block reduction: wave shuffle tree + LDS across 4 waves
    for (int o = 32; o > 0; o >>= 1) acc += __shfl_down(acc, o, 64);
    if ((tid & 63) == 0) wsum[tid >> 6] = acc;
    __syncthreads();
    if (tid == 0)
        partials[b] = (wsum[0] + wsum[1]) + (wsum[2] + wsum[3]);
}

// ---------------- Kernel 3: deterministic final reduce (applies ln2/P) ----------------
__global__ __launch_bounds__(256) void final_reduce(const float* __restrict__ partials,
                                                    float* __restrict__ out) {
    __shared__ float wsum[4];
    float acc = 0.0f;
    const float4* __restrict__ p4 = (const float4*)partials;   // 2500 = 625 float4s
    for (int t = threadIdx.x; t < NBLK / 4; t += 256) {
        const float4 v = p4[t];
        acc += (v.x + v.y) + (v.z + v.w);
    }
    for (int o = 32; o > 0; o >>= 1) acc += __shfl_down(acc, o, 64);
    if ((threadIdx.x & 63) == 0) wsum[threadIdx.x >> 6] = acc;
    __syncthreads();
    if (threadIdx.x == 0)
        out[0] = ((wsum[0] + wsum[1]) + (wsum[2] + wsum[3])) * (LN2 / PCOUNT);
}

extern "C" void kernel_launch(void* const* d_in, const int* in_sizes, int n_in,
                              void* d_out, int out_size, void* d_ws, size_t ws_size,
                              hipStream_t stream) {
    const float* x       = (const float*)d_in[0];   // (480,640) f32
    const float* gt      = (const float*)d_in[1];   // (P,) f32
    const int*   centers = (const int*)d_in[2];     // (5000,2) int32
    float* out = (float*)d_out;                     // scalar f32

    float* partials = (float*)d_ws;                 // NBLK floats
    __half* zs      = (__half*)(partials + NBLK);   // NR+2 halfs (scaled z)

    gather_z<<<(NR + 2 + 255) / 256, 256, 0, stream>>>(x, centers, zs);
    pair_loss<<<NBLK, 256, 0, stream>>>(gt, zs, partials);
    final_reduce<<<1, 256, 0, stream>>>(partials, out);
}

// Round 15
// 22.288 us; speedup vs baseline: 1.2372x; 1.2372x over previous
//
#include <hip/hip_runtime.h>
#include <hip/hip_fp16.h>
#include <stdint.h>

#define NR 5000
#define NRM1 4999
#define W 640
#define NBLK 2500          // block b: rows b and 4998-b, 8-padded virtual space
#define PTOT 12497500
#define PCOUNT 12497500.0f
#define LOG2E 1.44269504088896340736f
#define LN2   0.69314718055994530942f
#define NH2   2512         // half2 slots per parity array (covers 5008 halves + pad)

typedef float float4u __attribute__((ext_vector_type(4)));
struct __attribute__((packed, aligned(4))) f4wrap { float4u v; };
__device__ __forceinline__ float4u load4u(const float* p) {
    return ((const f4wrap*)p)->v;    // 4B-aligned vector load
}
__device__ __forceinline__ __half2 f2h2(float f) {
    union { float f; __half2 h; } u; u.f = f; return u.h;
}

// ---------------- Kernel 1: gather + scale + f16 + parity duplication ----------------
// zsA[i] = (zs[2i], zs[2i+1]); zsB[i] = (zs[2i+1], zs[2i+2]); zs = x[centers]*log2e, 0-padded.
__global__ void gather_z(const float* __restrict__ x,
                         const int* __restrict__ centers,
                         __half2* __restrict__ zsA,
                         __half2* __restrict__ zsB) {
    const int i = blockIdx.x * blockDim.x + threadIdx.x;
    if (i >= NH2) return;
    float v[3];
    #pragma unroll
    for (int e = 0; e < 3; ++e) {
        const int t = 2 * i + e;
        if (t < NR) {
            const int2 rc = ((const int2*)centers)[t];
            v[e] = x[rc.x * W + rc.y] * LOG2E;
        } else {
            v[e] = 0.0f;
        }
    }
    zsA[i] = __floats2half2_rn(v[0], v[1]);
    zsB[i] = __floats2half2_rn(v[1], v[2]);
}

// ---------------- Kernel 2: per-pair loss ----------------
// Loss per element (log2 domain; ln2 applied in final_reduce):
//   s = (z_j - z_r)*log2e;  lg = log2(1+2^(g*s));  l = lg + (1-g^2)*(s^2*ln2 - 1)
//   g=+-1 -> l = softplus(-g*d)/ln2 ; g=0 -> lg=1 exactly, l = d^2/ln2.
__global__ __launch_bounds__(256) void pair_loss(const float* __restrict__ gt,
                                                 const __half2* __restrict__ zsA,
                                                 const __half2* __restrict__ zsB,
                                                 float* __restrict__ partials) {
    __shared__ float wsum[4];
    const int tid = threadIdx.x;
    const int b = blockIdx.x;

    const int r1 = b, r2 = NR - 2 - b;
    const int len1 = NRM1 - b;
    const int len1p = (len1 + 7) & ~7;              // row2 starts 8-aligned
    const int len2 = (r2 > r1) ? (b + 1) : 0;
    const int vmaxp = len1p + len2;
    const int off1 = r1 * NRM1 - (r1 * (r1 - 1)) / 2;
    const int off2 = r2 * NRM1 - (r2 * (r2 - 1)) / 2;
    const int off2p = off2 - len1p;                 // gt index row2: off2p + c
    const int j1 = r1 + 1;                          // z index row1: c + j1
    const int j2 = r2 + 1 - len1p;                  // z index row2: c + j2 (may be <0)
    const __half2* __restrict__ pz1 = (j1 & 1) ? zsB : zsA;
    const __half2* __restrict__ pz2 = (j2 & 1) ? zsB : zsA;
    const int h1 = j1 >> 1;
    const int h2o = j2 >> 1;                        // arithmetic shift: floor, pairs with parity
    const int G = (vmaxp - 1) & ~7;                 // last group start

    const __half* __restrict__ zflat = (const __half*)zsA;
    const __half2 zr1h = __half2half2(zflat[r1]);
    const __half2 zr2h = __half2half2(zflat[r2]);
    const __half2 one2 = __float2half2_rn(1.0f);
    const __half2 ln2h = __float2half2_rn(LN2);
    const __half2 neg1 = __float2half2_rn(-1.0f);

    __half2 acc01 = __float2half2_rn(0.0f);
    __half2 acc23 = __float2half2_rn(0.0f);
    float accS = 0.0f;

    auto doGroup = [&](int vb) {
        const int c = min(vb, G);                   // stays 8-aligned
        const bool isr2 = c >= len1p;
        int gidx = (isr2 ? off2p : off1) + c;
        gidx = min(gidx, PTOT - 8);                 // OOB-safe for tail pad
        const float4u ga = load4u(gt + gidx);
        const float4u gb = load4u(gt + gidx + 4);
        const __half2* zb = isr2 ? pz2 : pz1;
        const int zi = (c >> 1) + (isr2 ? h2o : h1);
        const float4u zraw = load4u((const float*)zb + zi);   // 4 half2 = 8 z values
        const __half2 zr = isr2 ? zr2h : zr1h;
        const __half2 zj[4] = { f2h2(zraw.x), f2h2(zraw.y), f2h2(zraw.z), f2h2(zraw.w) };
        const __half2 gh[4] = { __floats2half2_rn(ga.x, ga.y), __floats2half2_rn(ga.z, ga.w),
                                __floats2half2_rn(gb.x, gb.y), __floats2half2_rn(gb.z, gb.w) };
        __half2 l[4];
        #pragma unroll
        for (int m = 0; m < 4; ++m) {
            const __half2 s  = __hsub2(zj[m], zr);
            const __half2 t  = __hmul2(gh[m], s);
            const __half2 lg = h2log2(__hadd2(h2exp2(t), one2));
            const __half2 q1 = __hfma2(__hmul2(s, ln2h), s, neg1);      // s^2*ln2 - 1
            const __half2 wm = __hfma2(__hneg2(gh[m]), gh[m], one2);    // 1 - g^2
            l[m] = __hfma2(wm, q1, lg);
        }
        const int lim = isr2 ? vmaxp : len1;        // valid-element limit for this group
        if (vb == c) {                              // clamped duplicates contribute nothing
            if (c + 8 <= lim) {                     // full group (hot path)
                acc01 = __hadd2(acc01, __hadd2(l[0], l[1]));
                acc23 = __hadd2(acc23, __hadd2(l[2], l[3]));
            } else {                                // rare: partial group, f32 scalar masking
                float fs = 0.0f;
                #pragma unroll
                for (int m = 0; m < 4; ++m) {
                    const float2 lf = __half22float2(l[m]);
                    if (c + 2 * m     < lim) fs += lf.x;
                    if (c + 2 * m + 1 < lim) fs += lf.y;
                }
                accS += fs;
            }
        }
    };

    doGroup(8 * tid);                               // groups 0..2040
    doGroup(8 * tid + 2048);                        // groups 2048..4088
    const int vb2 = 8 * tid + 4096;                 // groups 4096..6136 (partial coverage)
    if (vb2 <= G) doGroup(vb2);

    const float2 f01 = __half22float2(acc01);
    const float2 f23 = __half22float2(acc23);
    float acc = ((f01.x + f01.y) + (f23.x + f23.y)) + accS;

    // deterministic block reduction: wave shuffle tree + LDS across 4 waves
    for (int o = 32; o > 0; o >>= 1) acc += __shfl_down(acc, o, 64);
    if ((tid & 63) == 0) wsum[tid >> 6] = acc;
    __syncthreads();
    if (tid == 0)
        partials[b] = (wsum[0] + wsum[1]) + (wsum[2] + wsum[3]);
}

// ---------------- Kernel 3: deterministic final reduce (applies ln2/P) ----------------
__global__ __launch_bounds__(256) void final_reduce(const float* __restrict__ partials,
                                                    float* __restrict__ out) {
    __shared__ float wsum[4];
    float acc = 0.0f;
    const float4* __restrict__ p4 = (const float4*)partials;   // 2500 = 625 float4s
    for (int t = threadIdx.x; t < NBLK / 4; t += 256) {
        const float4 v = p4[t];
        acc += (v.x + v.y) + (v.z + v.w);
    }
    for (int o = 32; o > 0; o >>= 1) acc += __shfl_down(acc, o, 64);
    if ((threadIdx.x & 63) == 0) wsum[threadIdx.x >> 6] = acc;
    __syncthreads();
    if (threadIdx.x == 0)
        out[0] = ((wsum[0] + wsum[1]) + (wsum[2] + wsum[3])) * (LN2 / PCOUNT);
}

extern "C" void kernel_launch(void* const* d_in, const int* in_sizes, int n_in,
                              void* d_out, int out_size, void* d_ws, size_t ws_size,
                              hipStream_t stream) {
    const float* x       = (const float*)d_in[0];   // (480,640) f32
    const float* gt      = (const float*)d_in[1];   // (P,) f32
    const int*   centers = (const int*)d_in[2];     // (5000,2) int32
    float* out = (float*)d_out;                     // scalar f32

    __half2* zsA   = (__half2*)d_ws;                // NH2 half2
    __half2* zsB   = zsA + NH2;                     // NH2 half2
    float* partials = (float*)(zsB + NH2);          // NBLK floats (16B aligned)

    gather_z<<<(NH2 + 255) / 256, 256, 0, stream>>>(x, centers, zsA, zsB);
    pair_loss<<<NBLK, 256, 0, stream>>>(gt, zsA, zsB, partials);
    final_reduce<<<1, 256, 0, stream>>>(partials, out);
}

// Round 16
// 22.155 us; speedup vs baseline: 1.2447x; 1.0060x over previous
//
#include <hip/hip_runtime.h>
#include <hip/hip_fp16.h>
#include <stdint.h>

#define NR 5000
#define NRM1 4999
#define W 640
#define NBLK 2500          // block b: rows b and 4998-b, 16-padded virtual space
#define PTOT 12497500
#define PCOUNT 12497500.0f
#define LOG2E 1.44269504088896340736f
#define LN2   0.69314718055994530942f
#define NH2   2520         // half2 slots per parity array (covers 5040 halves incl pad)

typedef float float4u __attribute__((ext_vector_type(4)));
struct __attribute__((packed, aligned(4))) f4wrap { float4u v; };
__device__ __forceinline__ float4u load4u(const float* p) {
    return ((const f4wrap*)p)->v;    // 4B-aligned vector load
}
__device__ __forceinline__ __half2 f2h2(float f) {
    union { float f; __half2 h; } u; u.f = f; return u.h;
}

// ---------------- Kernel 1: gather + scale + f16 + parity duplication ----------------
// zsA[i] = (zs[2i], zs[2i+1]); zsB[i] = (zs[2i+1], zs[2i+2]); zs = x[centers]*log2e, 0-padded.
__global__ void gather_z(const float* __restrict__ x,
                         const int* __restrict__ centers,
                         __half2* __restrict__ zsA,
                         __half2* __restrict__ zsB) {
    const int i = blockIdx.x * blockDim.x + threadIdx.x;
    if (i >= NH2) return;
    float v[3];
    #pragma unroll
    for (int e = 0; e < 3; ++e) {
        const int t = 2 * i + e;
        if (t < NR) {
            const int2 rc = ((const int2*)centers)[t];
            v[e] = x[rc.x * W + rc.y] * LOG2E;
        } else {
            v[e] = 0.0f;
        }
    }
    zsA[i] = __floats2half2_rn(v[0], v[1]);
    zsB[i] = __floats2half2_rn(v[1], v[2]);
}

// ---------------- Kernel 2: per-pair loss (16-elem groups) ----------------
// Loss per element (log2 domain; ln2 applied in final_reduce):
//   s = (z_j - z_r)*log2e;  lg = log2(1+2^(g*s));  l = lg + (1-g^2)*(s^2*ln2 - 1)
//   g=+-1 -> softplus(-g*d)/ln2 ; g=0 -> lg=1 exactly, l = d^2/ln2.
__global__ __launch_bounds__(256) void pair_loss(const float* __restrict__ gt,
                                                 const __half2* __restrict__ zsA,
                                                 const __half2* __restrict__ zsB,
                                                 float* __restrict__ partials) {
    __shared__ float wsum[4];
    const int tid = threadIdx.x;
    const int b = blockIdx.x;

    const int r1 = b, r2 = NR - 2 - b;
    const int len1 = NRM1 - b;
    const int len1p = (len1 + 15) & ~15;            // row2 starts 16-aligned
    const int len2 = (r2 > r1) ? (b + 1) : 0;
    const int vmaxp = len1p + len2;
    const int off1 = r1 * NRM1 - (r1 * (r1 - 1)) / 2;
    const int off2 = r2 * NRM1 - (r2 * (r2 - 1)) / 2;
    const int off2p = off2 - len1p;                 // gt index row2: off2p + c
    const int j1 = r1 + 1;                          // z index row1: c + j1
    const int j2 = r2 + 1 - len1p;                  // z index row2: c + j2 (may be <0)
    const __half2* __restrict__ pz1 = (j1 & 1) ? zsB : zsA;
    const __half2* __restrict__ pz2 = (j2 & 1) ? zsB : zsA;
    const int h1 = j1 >> 1;
    const int h2o = j2 >> 1;                        // arithmetic shift: floor
    const int G = (vmaxp - 1) & ~15;                // last group start

    const __half* __restrict__ zflat = (const __half*)zsA;
    const __half2 zr1h = __half2half2(zflat[r1]);
    const __half2 zr2h = __half2half2(zflat[r2]);
    const __half2 one2 = __float2half2_rn(1.0f);
    const __half2 ln2h = __float2half2_rn(LN2);
    const __half2 neg1 = __float2half2_rn(-1.0f);

    __half2 accA = __float2half2_rn(0.0f);
    __half2 accB = __float2half2_rn(0.0f);
    float accS = 0.0f;

    auto doGroup = [&](int vb) {
        const int c = min(vb, G);                   // stays 16-aligned
        const bool isr2 = c >= len1p;
        int gidx = (isr2 ? off2p : off1) + c;
        gidx = min(gidx, PTOT - 16);                // OOB-safe for tail pad
        const float4u ga = load4u(gt + gidx);
        const float4u gb = load4u(gt + gidx + 4);
        const float4u gc = load4u(gt + gidx + 8);
        const float4u gd = load4u(gt + gidx + 12);
        const __half2* zb = isr2 ? pz2 : pz1;
        const int zi = (c >> 1) + (isr2 ? h2o : h1);
        const float4u zr0 = load4u((const float*)zb + zi);       // halfs [0..8)
        const float4u zr1_ = load4u((const float*)zb + zi + 4);  // halfs [8..16)
        const __half2 zr = isr2 ? zr2h : zr1h;
        const __half2 zj[8] = { f2h2(zr0.x), f2h2(zr0.y), f2h2(zr0.z), f2h2(zr0.w),
                                f2h2(zr1_.x), f2h2(zr1_.y), f2h2(zr1_.z), f2h2(zr1_.w) };
        const __half2 gh[8] = {
            __floats2half2_rn(ga.x, ga.y), __floats2half2_rn(ga.z, ga.w),
            __floats2half2_rn(gb.x, gb.y), __floats2half2_rn(gb.z, gb.w),
            __floats2half2_rn(gc.x, gc.y), __floats2half2_rn(gc.z, gc.w),
            __floats2half2_rn(gd.x, gd.y), __floats2half2_rn(gd.z, gd.w) };
        __half2 l[8];
        #pragma unroll
        for (int m = 0; m < 8; ++m) {
            const __half2 s  = __hsub2(zj[m], zr);
            const __half2 t  = __hmul2(gh[m], s);
            const __half2 lg = h2log2(__hadd2(h2exp2(t), one2));
            const __half2 q1 = __hfma2(__hmul2(s, ln2h), s, neg1);      // s^2*ln2 - 1
            const __half2 wm = __hfma2(__hneg2(gh[m]), gh[m], one2);    // 1 - g^2
            l[m] = __hfma2(wm, q1, lg);
        }
        const int lim = isr2 ? vmaxp : len1;        // valid-element limit
        if (vb == c) {                              // clamped duplicates contribute nothing
            if (c + 16 <= lim) {                    // full group (hot path)
                const __half2 s01 = __hadd2(__hadd2(l[0], l[1]), __hadd2(l[2], l[3]));
                const __half2 s23 = __hadd2(__hadd2(l[4], l[5]), __hadd2(l[6], l[7]));
                accA = __hadd2(accA, s01);
                accB = __hadd2(accB, s23);
            } else {                                // rare: partial tail group, f32 masking
                float fs = 0.0f;
                #pragma unroll
                for (int m = 0; m < 8; ++m) {
                    const float2 lf = __half22float2(l[m]);
                    if (c + 2 * m     < lim) fs += lf.x;
                    if (c + 2 * m + 1 < lim) fs += lf.y;
                }
                accS += fs;
            }
        }
    };

    doGroup(16 * tid);                              // groups 0..4080
    const int vb2 = 16 * tid + 4096;                // groups 4096..  (tail coverage)
    if (vb2 <= G) doGroup(vb2);

    const float2 fA = __half22float2(accA);
    const float2 fB = __half22float2(accB);
    float acc = ((fA.x + fA.y) + (fB.x + fB.y)) + accS;

    // deterministic block reduction: wave shuffle tree + LDS across 4 waves
    for (int o = 32; o > 0; o >>= 1) acc += __shfl_down(acc, o, 64);
    if ((tid & 63) == 0) wsum[tid >> 6] = acc;
    __syncthreads();
    if (tid == 0)
        partials[b] = (wsum[0] + wsum[1]) + (wsum[2] + wsum[3]);
}

// ---------------- Kernel 3: deterministic final reduce (applies ln2/P) ----------------
__global__ __launch_bounds__(256) void final_reduce(const float* __restrict__ partials,
                                                    float* __restrict__ out) {
    __shared__ float wsum[4];
    float acc = 0.0f;
    const float4* __restrict__ p4 = (const float4*)partials;   // 2500 = 625 float4s
    for (int t = threadIdx.x; t < NBLK / 4; t += 256) {
        const float4 v = p4[t];
        acc += (v.x + v.y) + (v.z + v.w);
    }
    for (int o = 32; o > 0; o >>= 1) acc += __shfl_down(acc, o, 64);
    if ((threadIdx.x & 63) == 0) wsum[threadIdx.x >> 6] = acc;
    __syncthreads();
    if (threadIdx.x == 0)
        out[0] = ((wsum[0] + wsum[1]) + (wsum[2] + wsum[3])) * (LN2 / PCOUNT);
}

extern "C" void kernel_launch(void* const* d_in, const int* in_sizes, int n_in,
                              void* d_out, int out_size, void* d_ws, size_t ws_size,
                              hipStream_t stream) {
    const float* x       = (const float*)d_in[0];   // (480,640) f32
    const float* gt      = (const float*)d_in[1];   // (P,) f32
    const int*   centers = (const int*)d_in[2];     // (5000,2) int32
    float* out = (float*)d_out;                     // scalar f32

    __half2* zsA   = (__half2*)d_ws;                // NH2 half2
    __half2* zsB   = zsA + NH2;                     // NH2 half2
    float* partials = (float*)(zsB + NH2);          // NBLK floats (16B aligned)

    gather_z<<<(NH2 + 255) / 256, 256, 0, stream>>>(x, centers, zsA, zsB);
    pair_loss<<<NBLK, 256, 0, stream>>>(gt, zsA, zsB, partials);
    final_reduce<<<1, 256, 0, stream>>>(partials, out);
}